// Round 1
// baseline (766.600 us; speedup 1.0000x reference)
//
#include <hip/hip_runtime.h>
#include <hip/hip_bf16.h>
#include <math.h>

#define Q 32
#define BQ 64          // B*Q
#define HH 128         // hidden dim
#define EPS 1e-8f

__device__ __forceinline__ float gelu_exact(float x) {
    return 0.5f * x * (1.0f + erff(x * 0.70710678118654752440f));
}

// ---------------------------------------------------------------------------
// FiLM projection: gb[bq, 0:2C] = q[bq] @ film_w + film_b
// and bias2[bq, j] = hid_b[j] + sum_c beta[c] * hid_w[c,j]
// grid: 64 blocks (one per (b,q)), 256 threads
// ---------------------------------------------------------------------------
__global__ __launch_bounds__(256)
void film_kernel(const float* __restrict__ qe,      // [BQ][768]
                 const float* __restrict__ film_w,  // [768][2C]
                 const float* __restrict__ film_b,  // [2C]
                 int C,
                 const float* __restrict__ hid_w,   // [C][128]
                 const float* __restrict__ hid_b,   // [128]
                 float* __restrict__ gb_out,        // [BQ][2C]
                 float* __restrict__ b2_out)        // [BQ][128]
{
    __shared__ float sq[768];
    __shared__ float sBeta[256];   // max C
    const int tid = threadIdx.x;
    const int bq  = blockIdx.x;
    for (int i = tid; i < 768; i += 256) sq[i] = qe[bq * 768 + i];
    __syncthreads();
    const int twoC = 2 * C;
    for (int o = tid; o < twoC; o += 256) {
        float s = film_b[o];
        #pragma unroll 4
        for (int e = 0; e < 768; ++e)
            s = fmaf(sq[e], film_w[e * twoC + o], s);
        gb_out[bq * twoC + o] = s;
        if (o >= C) sBeta[o - C] = s;
    }
    __syncthreads();
    if (tid < HH) {
        float s = hid_b[tid];
        for (int c = 0; c < C; ++c)
            s = fmaf(sBeta[c], hid_w[c * HH + tid], s);
        b2_out[bq * HH + tid] = s;
    }
}

// ---------------------------------------------------------------------------
// FiLM pool: per (bq, hw) compute attn = sigmoid(gelu(h) . fin_w + fin_b)
// with h = f . (gamma*W) + bias2, then accumulate S_fc[c] = sum attn*f[c],
// S_a = sum attn into Sout[bq][C+1] via atomics.
// grid: (BQ, ntiles), 256 threads, thread-per-hw
// ---------------------------------------------------------------------------
template<int C>
__global__ __launch_bounds__(256)
void pool_kernel(const float* __restrict__ feat,   // [B][C][HW]
                 int HW,
                 const float* __restrict__ gb,     // [BQ][2C]  (gamma|beta)
                 const float* __restrict__ b2,     // [BQ][128]
                 const float* __restrict__ hid_w,  // [C][128]
                 const float* __restrict__ fin_w,  // [128]
                 const float* __restrict__ fin_b,  // [1]
                 float* __restrict__ Sout,         // [BQ][C+1]
                 float* __restrict__ attn_out)     // [BQ][HW] or null
{
    constexpr int JC = 32;              // hidden-chunk size
    __shared__ float sW[C * JC];        // gamma-scaled weight chunk
    __shared__ float sFin[HH];
    __shared__ float sAttn[256];
    __shared__ float sRed[4];

    const int tid = threadIdx.x;
    const int bq  = blockIdx.x;
    const int b   = bq >> 5;            // / Q
    const int hw0 = blockIdx.y * 256;
    const int hw  = hw0 + tid;
    const bool valid = hw < HW;
    const int hwc = valid ? hw : (HW - 1);

    const float* fb = feat + (size_t)b * C * HW;
    const float* g  = gb + bq * 2 * C;          // gamma at [0,C), beta at [C,2C)
    const float* bb = b2 + bq * HH;

    if (tid < HH) sFin[tid] = fin_w[tid];

    float attn_logit = fin_b[0];

    for (int jo = 0; jo < HH / JC; ++jo) {
        __syncthreads();
        // stage Wq chunk: sW[c][j] = gamma[c] * hid_w[c][jo*JC + j]
        for (int i = tid; i < C * JC; i += 256) {
            int c = i / JC;
            int j = i & (JC - 1);
            sW[i] = g[c] * hid_w[c * HH + jo * JC + j];
        }
        __syncthreads();

        float acc[JC];
        #pragma unroll
        for (int j = 0; j < JC; ++j) acc[j] = bb[jo * JC + j];

        #pragma unroll 2
        for (int c = 0; c < C; ++c) {
            float fv = fb[(size_t)c * HW + hwc];
            #pragma unroll
            for (int j = 0; j < JC; ++j)
                acc[j] = fmaf(fv, sW[c * JC + j], acc[j]);
        }

        #pragma unroll
        for (int j = 0; j < JC; ++j) {
            float ge = gelu_exact(acc[j]);
            attn_logit = fmaf(ge, sFin[jo * JC + j], attn_logit);
        }
    }

    float attn = valid ? (1.0f / (1.0f + expf(-attn_logit))) : 0.0f;
    if (attn_out != nullptr && valid) attn_out[bq * HW + hw] = attn;

    sAttn[tid] = attn;
    // wave-level reduce of attn for S_a
    float s = attn;
    #pragma unroll
    for (int d = 1; d < 64; d <<= 1) s += __shfl_xor(s, d);
    if ((tid & 63) == 0) sRed[tid >> 6] = s;
    __syncthreads();

    const int limit = min(256, HW - hw0);
    if (tid < C) {
        float acc2 = 0.0f;
        const float* fr = fb + (size_t)tid * HW + hw0;
        #pragma unroll 4
        for (int i = 0; i < limit; ++i)
            acc2 = fmaf(sAttn[i], fr[i], acc2);
        atomicAdd(&Sout[bq * (C + 1) + tid], acc2);
    }
    if (tid == 0) {
        float sa = sRed[0] + sRed[1] + sRed[2] + sRed[3];
        atomicAdd(&Sout[bq * (C + 1) + C], sa);
    }
}

// ---------------------------------------------------------------------------
// Final: assemble cat = [p0, p1, p2, a2] (848) and run the 3-layer MLP.
// grid: 64 blocks (one per bq), 256 threads
// ---------------------------------------------------------------------------
__global__ __launch_bounds__(256)
void final_kernel(const float* __restrict__ S0, const float* __restrict__ S1,
                  const float* __restrict__ S2,
                  const float* __restrict__ gb0, const float* __restrict__ gb1,
                  const float* __restrict__ gb2,
                  const float* __restrict__ attn2,   // [BQ][400]
                  const float* __restrict__ w1, const float* __restrict__ b1,
                  const float* __restrict__ w2, const float* __restrict__ b2,
                  const float* __restrict__ w3, const float* __restrict__ b3,
                  float* __restrict__ out)           // [BQ]
{
    __shared__ float sCat[848];
    __shared__ float sX1[512];
    __shared__ float sX2[256];
    __shared__ float sR[4];
    const int tid = threadIdx.x;
    const int bq  = blockIdx.x;

    for (int i = tid; i < 448; i += 256) {
        int sc, c;
        if (i < 64)       { sc = 0; c = i; }
        else if (i < 192) { sc = 1; c = i - 64; }
        else              { sc = 2; c = i - 192; }
        const int C = 64 << sc;
        const float* So = (sc == 0) ? S0 : (sc == 1) ? S1 : S2;
        const float* g  = (sc == 0) ? gb0 : (sc == 1) ? gb1 : gb2;
        float Sa = So[bq * (C + 1) + C];
        float Sf = So[bq * (C + 1) + c];
        float gamma = g[bq * 2 * C + c];
        float beta  = g[bq * 2 * C + C + c];
        sCat[i] = (gamma * Sf + beta * Sa) / (Sa + EPS);
    }
    for (int i = tid; i < 400; i += 256) sCat[448 + i] = attn2[bq * 400 + i];
    __syncthreads();

    for (int o = tid; o < 512; o += 256) {
        float s = b1[o];
        #pragma unroll 4
        for (int k = 0; k < 848; ++k) s = fmaf(sCat[k], w1[k * 512 + o], s);
        sX1[o] = gelu_exact(s);
    }
    __syncthreads();
    {
        float s = b2[tid];
        #pragma unroll 4
        for (int k = 0; k < 512; ++k) s = fmaf(sX1[k], w2[k * 256 + tid], s);
        sX2[tid] = gelu_exact(s);
    }
    __syncthreads();
    float p = sX2[tid] * w3[tid];
    #pragma unroll
    for (int d = 1; d < 64; d <<= 1) p += __shfl_xor(p, d);
    if ((tid & 63) == 0) sR[tid >> 6] = p;
    __syncthreads();
    if (tid == 0) out[bq] = sR[0] + sR[1] + sR[2] + sR[3] + b3[0];
}

// ---------------------------------------------------------------------------
extern "C" void kernel_launch(void* const* d_in, const int* in_sizes, int n_in,
                              void* d_out, int out_size, void* d_ws, size_t ws_size,
                              hipStream_t stream)
{
    const float* feat0 = (const float*)d_in[0];   // [2][64][6400]
    const float* feat1 = (const float*)d_in[1];   // [2][128][1600]
    const float* feat2 = (const float*)d_in[2];   // [2][256][400]
    const float* qe    = (const float*)d_in[3];   // [2][32][768]
    const float* film_w0 = (const float*)d_in[4];
    const float* film_b0 = (const float*)d_in[5];
    const float* hid_w0  = (const float*)d_in[6];
    const float* hid_b0  = (const float*)d_in[7];
    const float* fin_w0  = (const float*)d_in[8];
    const float* fin_b0  = (const float*)d_in[9];
    const float* film_w1 = (const float*)d_in[10];
    const float* film_b1 = (const float*)d_in[11];
    const float* hid_w1  = (const float*)d_in[12];
    const float* hid_b1  = (const float*)d_in[13];
    const float* fin_w1  = (const float*)d_in[14];
    const float* fin_b1  = (const float*)d_in[15];
    const float* film_w2 = (const float*)d_in[16];
    const float* film_b2 = (const float*)d_in[17];
    const float* hid_w2  = (const float*)d_in[18];
    const float* hid_b2  = (const float*)d_in[19];
    const float* fin_w2  = (const float*)d_in[20];
    const float* fin_b2  = (const float*)d_in[21];
    const float* mlp_w1  = (const float*)d_in[22];
    const float* mlp_b1  = (const float*)d_in[23];
    const float* mlp_w2  = (const float*)d_in[24];
    const float* mlp_b2  = (const float*)d_in[25];
    const float* mlp_w3  = (const float*)d_in[26];
    const float* mlp_b3  = (const float*)d_in[27];

    float* ws = (float*)d_ws;
    // workspace layout (floats)
    float* S0    = ws;                     // [64][65]   = 4160
    float* S1    = ws + 4160;              // [64][129]  = 8256
    float* S2    = ws + 12416;             // [64][257]  = 16448  -> Sout total 28864
    float* gb0   = ws + 28864;             // [64][128]  = 8192
    float* gb1   = ws + 37056;             // [64][256]  = 16384
    float* gb2   = ws + 53440;             // [64][512]  = 32768
    float* b20   = ws + 86208;             // [64][128]  = 8192
    float* b21   = ws + 94400;             // [64][128]
    float* b22   = ws + 102592;            // [64][128]
    float* attn2 = ws + 110784;            // [64][400]  = 25600  (end 136384 floats)

    // zero the atomic accumulators (fresh every call for graph replay)
    hipMemsetAsync(d_ws, 0, 28864 * sizeof(float), stream);

    film_kernel<<<64, 256, 0, stream>>>(qe, film_w0, film_b0, 64,  hid_w0, hid_b0, gb0, b20);
    film_kernel<<<64, 256, 0, stream>>>(qe, film_w1, film_b1, 128, hid_w1, hid_b1, gb1, b21);
    film_kernel<<<64, 256, 0, stream>>>(qe, film_w2, film_b2, 256, hid_w2, hid_b2, gb2, b22);

    pool_kernel<64><<<dim3(BQ, 25), 256, 0, stream>>>(feat0, 6400, gb0, b20, hid_w0, fin_w0, fin_b0, S0, nullptr);
    pool_kernel<128><<<dim3(BQ, 7), 256, 0, stream>>>(feat1, 1600, gb1, b21, hid_w1, fin_w1, fin_b1, S1, nullptr);
    pool_kernel<256><<<dim3(BQ, 2), 256, 0, stream>>>(feat2, 400,  gb2, b22, hid_w2, fin_w2, fin_b2, S2, attn2);

    final_kernel<<<BQ, 256, 0, stream>>>(S0, S1, S2, gb0, gb1, gb2, attn2,
                                         mlp_w1, mlp_b1, mlp_w2, mlp_b2, mlp_w3, mlp_b3,
                                         (float*)d_out);
}

// Round 2
// 449.182 us; speedup vs baseline: 1.7067x; 1.7067x over previous
//
#include <hip/hip_runtime.h>
#include <math.h>

#define BQ 64
#define HH 128
#define EPS 1e-8f

__device__ __forceinline__ float gelu_exact(float x) {
    return 0.5f * x * (1.0f + erff(x * 0.70710678118654752440f));
}

// ---------------------------------------------------------------------------
// FiLM projection (all 3 scales in one launch): gb = q @ film_w + film_b,
// b2[j] = hid_b[j] + sum_c beta[c] * hid_w[c,j]
// grid (BQ, 3), 256 threads
// ---------------------------------------------------------------------------
__global__ __launch_bounds__(256)
void film_fused(const float* __restrict__ qe,
                const float* __restrict__ fw0, const float* __restrict__ fb0,
                const float* __restrict__ hw0_, const float* __restrict__ hb0,
                const float* __restrict__ fw1, const float* __restrict__ fb1,
                const float* __restrict__ hw1_, const float* __restrict__ hb1,
                const float* __restrict__ fw2, const float* __restrict__ fb2,
                const float* __restrict__ hw2_, const float* __restrict__ hb2,
                float* __restrict__ gb0, float* __restrict__ gb1, float* __restrict__ gb2,
                float* __restrict__ b20, float* __restrict__ b21, float* __restrict__ b22)
{
    __shared__ float sq[768];
    __shared__ float sBeta[256];
    __shared__ float sB2[256];
    const int tid = threadIdx.x, bq = blockIdx.x, s = blockIdx.y;
    const float* fw = s == 0 ? fw0 : s == 1 ? fw1 : fw2;
    const float* fbv = s == 0 ? fb0 : s == 1 ? fb1 : fb2;
    const float* hw = s == 0 ? hw0_ : s == 1 ? hw1_ : hw2_;
    const float* hb = s == 0 ? hb0 : s == 1 ? hb1 : hb2;
    float* gb = s == 0 ? gb0 : s == 1 ? gb1 : gb2;
    float* b2 = s == 0 ? b20 : s == 1 ? b21 : b22;
    const int C = 64 << s, twoC = 2 * C;

    for (int i = tid; i < 768; i += 256) sq[i] = qe[bq * 768 + i];
    __syncthreads();

    for (int o = tid; o < twoC; o += 256) {
        float a0 = fbv[o], a1 = 0.f;
        #pragma unroll 2
        for (int e = 0; e < 768; e += 2) {
            a0 = fmaf(sq[e],     fw[e * twoC + o],       a0);
            a1 = fmaf(sq[e + 1], fw[(e + 1) * twoC + o], a1);
        }
        float r = a0 + a1;
        gb[bq * twoC + o] = r;
        if (o >= C) sBeta[o - C] = r;
    }
    __syncthreads();
    {
        const int j = tid & 127, h = tid >> 7;
        const int c0 = h * (C / 2);
        float acc = 0.f;
        for (int c = 0; c < C / 2; ++c)
            acc = fmaf(sBeta[c0 + c], hw[(c0 + c) * HH + j], acc);
        sB2[tid] = acc;
    }
    __syncthreads();
    if (tid < 128) b2[bq * HH + tid] = hb[tid] + sB2[tid] + sB2[128 + tid];
}

// ---------------------------------------------------------------------------
// Fused FiLM pool, all scales one launch. Block = 4 waves; wave w owns
// hidden slice j in [32w, 32w+32); each wave stages its own gamma*W slice
// (no barriers in main loop). 2 px per lane, 128 px per block.
// ---------------------------------------------------------------------------
template<int C, bool WRITE_ATTN>
__device__ __forceinline__
void pool_body(const float* __restrict__ feat, int HW,
               const float* __restrict__ gb, const float* __restrict__ b2,
               const float* __restrict__ hidw, const float* __restrict__ finw,
               const float* __restrict__ finb,
               float* __restrict__ Sout, float* __restrict__ attn_out,
               int bq, int tile,
               float* sW, float* sAttn, float* sPlog, float* sRed)
{
    const int tid = threadIdx.x;
    const int w = tid >> 6, lane = tid & 63;
    const int b = bq >> 5;
    const int hw0 = tile * 128;
    const float* fbase = feat + (size_t)b * C * HW;
    const float* g = gb + bq * 2 * C;            // gamma at [0,C)
    const int pxb = hw0 + lane * 2;
    const int pxc = min(pxb, HW - 2);            // clamped load base (HW even)

    float acc0[32], acc1[32];
    #pragma unroll
    for (int j = 0; j < 32; ++j) {
        float bv = b2[bq * HH + w * 32 + j];
        acc0[j] = bv; acc1[j] = bv;
    }

    float* myW = sW + w * 2048;                  // 64c x 32j slice
    constexpr int NCC = C / 64;
    for (int cc = 0; cc < NCC; ++cc) {
        #pragma unroll 8
        for (int i = 0; i < 32; ++i) {
            int idx = i * 64 + lane;
            int cl = idx >> 5, j = idx & 31;
            int c = cc * 64 + cl;
            myW[idx] = g[c] * hidw[c * HH + w * 32 + j];
        }
        // same-wave ds_write -> ds_read ordering handled by compiler waitcnt
        #pragma unroll 2
        for (int c = 0; c < 64; ++c) {
            const float2 fv = *(const float2*)(fbase + (size_t)(cc * 64 + c) * HW + pxc);
            const float4* wp = (const float4*)(myW + c * 32);
            #pragma unroll
            for (int q = 0; q < 8; ++q) {
                float4 wv = wp[q];
                acc0[q * 4 + 0] = fmaf(fv.x, wv.x, acc0[q * 4 + 0]);
                acc0[q * 4 + 1] = fmaf(fv.x, wv.y, acc0[q * 4 + 1]);
                acc0[q * 4 + 2] = fmaf(fv.x, wv.z, acc0[q * 4 + 2]);
                acc0[q * 4 + 3] = fmaf(fv.x, wv.w, acc0[q * 4 + 3]);
                acc1[q * 4 + 0] = fmaf(fv.y, wv.x, acc1[q * 4 + 0]);
                acc1[q * 4 + 1] = fmaf(fv.y, wv.y, acc1[q * 4 + 1]);
                acc1[q * 4 + 2] = fmaf(fv.y, wv.z, acc1[q * 4 + 2]);
                acc1[q * 4 + 3] = fmaf(fv.y, wv.w, acc1[q * 4 + 3]);
            }
        }
    }

    // gelu + partial attn logit over this wave's 32 hidden units
    float pl0 = 0.f, pl1 = 0.f;
    #pragma unroll
    for (int j = 0; j < 32; ++j) {
        float fwv = finw[w * 32 + j];
        pl0 = fmaf(gelu_exact(acc0[j]), fwv, pl0);
        pl1 = fmaf(gelu_exact(acc1[j]), fwv, pl1);
    }
    sPlog[w * 128 + lane * 2]     = pl0;
    sPlog[w * 128 + lane * 2 + 1] = pl1;
    __syncthreads();

    if (tid < 128) {
        float lg = finb[0] + sPlog[tid] + sPlog[128 + tid] + sPlog[256 + tid] + sPlog[384 + tid];
        int px = hw0 + tid;
        float a = (px < HW) ? 1.f / (1.f + expf(-lg)) : 0.f;
        sAttn[tid] = a;
        if (WRITE_ATTN && px < HW) attn_out[bq * HW + px] = a;
        float sa = a;
        #pragma unroll
        for (int d = 1; d < 64; d <<= 1) sa += __shfl_xor(sa, d);
        if ((tid & 63) == 0) sRed[tid >> 6] = sa;
    }
    __syncthreads();
    if (tid == 0) atomicAdd(&Sout[bq * (C + 1) + C], sRed[0] + sRed[1]);

    // S_fc[c] = sum_px attn * f[c,px]
    {
        const int c = tid & (C - 1);
        const int part = tid / C;                 // uniform within a wave
        const int per = 256 / C;
        const int cnt = 128 / per;
        const int i0 = part * cnt;
        const int lim = min(cnt, HW - hw0 - i0);
        if (lim > 0) {
            float s0 = 0.f, s1 = 0.f;
            const float* fr = fbase + (size_t)c * HW + hw0 + i0;
            int i = 0;
            for (; i + 1 < lim; i += 2) {
                s0 = fmaf(sAttn[i0 + i],     fr[i],     s0);
                s1 = fmaf(sAttn[i0 + i + 1], fr[i + 1], s1);
            }
            if (i < lim) s0 = fmaf(sAttn[i0 + i], fr[i], s0);
            atomicAdd(&Sout[bq * (C + 1) + c], s0 + s1);
        }
    }
}

__global__ __launch_bounds__(256)
void pool_fused(const float* __restrict__ feat0, const float* __restrict__ feat1,
                const float* __restrict__ feat2,
                const float* __restrict__ gb0, const float* __restrict__ gb1,
                const float* __restrict__ gb2,
                const float* __restrict__ b20, const float* __restrict__ b21,
                const float* __restrict__ b22,
                const float* __restrict__ hw0_, const float* __restrict__ hw1_,
                const float* __restrict__ hw2_,
                const float* __restrict__ finw0, const float* __restrict__ finb0,
                const float* __restrict__ finw1, const float* __restrict__ finb1,
                const float* __restrict__ finw2, const float* __restrict__ finb2,
                float* __restrict__ S0, float* __restrict__ S1, float* __restrict__ S2,
                float* __restrict__ attn2)
{
    __shared__ float sW[8192];      // 4 waves * 64c * 32j
    __shared__ float sAttn[128];
    __shared__ float sPlog[512];
    __shared__ float sRed[2];
    const int blk = blockIdx.x;
    if (blk < 256) {                              // scale 2 first (heaviest)
        int bq = blk >> 2, t = blk & 3;
        pool_body<256, true>(feat2, 400, gb2, b22, hw2_, finw2, finb2,
                             S2, attn2, bq, t, sW, sAttn, sPlog, sRed);
    } else if (blk < 256 + 832) {
        int bb = blk - 256; int bq = bb / 13, t = bb % 13;
        pool_body<128, false>(feat1, 1600, gb1, b21, hw1_, finw1, finb1,
                              S1, nullptr, bq, t, sW, sAttn, sPlog, sRed);
    } else {
        int bb = blk - 1088; int bq = bb / 50, t = bb % 50;
        pool_body<64, false>(feat0, 6400, gb0, b20, hw0_, finw0, finb0,
                             S0, nullptr, bq, t, sW, sAttn, sPlog, sRed);
    }
}

// ---------------------------------------------------------------------------
// MLP layer 1: X1[bq, o] = cat(bq) . w1[:,o] + b1[o]   (pre-gelu)
// grid (BQ, 2), 256 threads
// ---------------------------------------------------------------------------
__global__ __launch_bounds__(256)
void mlp1_kernel(const float* __restrict__ S0, const float* __restrict__ S1,
                 const float* __restrict__ S2,
                 const float* __restrict__ gb0, const float* __restrict__ gb1,
                 const float* __restrict__ gb2,
                 const float* __restrict__ attn2,
                 const float* __restrict__ w1, const float* __restrict__ b1,
                 float* __restrict__ X1)
{
    __shared__ float sCat[848];
    const int tid = threadIdx.x, bq = blockIdx.x, half = blockIdx.y;

    for (int i = tid; i < 448; i += 256) {
        int sc, c;
        if (i < 64)       { sc = 0; c = i; }
        else if (i < 192) { sc = 1; c = i - 64; }
        else              { sc = 2; c = i - 192; }
        const int C = 64 << sc;
        const float* So = (sc == 0) ? S0 : (sc == 1) ? S1 : S2;
        const float* g  = (sc == 0) ? gb0 : (sc == 1) ? gb1 : gb2;
        float Sa = So[bq * (C + 1) + C];
        float Sf = So[bq * (C + 1) + c];
        float gamma = g[bq * 2 * C + c];
        float beta  = g[bq * 2 * C + C + c];
        sCat[i] = (gamma * Sf + beta * Sa) / (Sa + EPS);
    }
    for (int i = tid; i < 400; i += 256) sCat[448 + i] = attn2[bq * 400 + i];
    __syncthreads();

    const int o = half * 256 + tid;
    float a0 = b1[o], a1 = 0.f;
    #pragma unroll 2
    for (int k = 0; k < 848; k += 2) {
        a0 = fmaf(sCat[k],     w1[k * 512 + o],       a0);
        a1 = fmaf(sCat[k + 1], w1[(k + 1) * 512 + o], a1);
    }
    X1[bq * 512 + o] = a0 + a1;
}

// ---------------------------------------------------------------------------
// MLP layers 2+3. grid BQ, 256 threads
// ---------------------------------------------------------------------------
__global__ __launch_bounds__(256)
void mlp23_kernel(const float* __restrict__ X1,
                  const float* __restrict__ w2, const float* __restrict__ b2,
                  const float* __restrict__ w3, const float* __restrict__ b3,
                  float* __restrict__ out)
{
    __shared__ float sX1[512];
    __shared__ float sX2[256];
    __shared__ float sR[4];
    const int tid = threadIdx.x, bq = blockIdx.x;
    for (int i = tid; i < 512; i += 256) sX1[i] = gelu_exact(X1[bq * 512 + i]);
    __syncthreads();
    float a0 = b2[tid], a1 = 0.f;
    #pragma unroll 2
    for (int k = 0; k < 512; k += 2) {
        a0 = fmaf(sX1[k],     w2[k * 256 + tid],       a0);
        a1 = fmaf(sX1[k + 1], w2[(k + 1) * 256 + tid], a1);
    }
    sX2[tid] = gelu_exact(a0 + a1);
    __syncthreads();
    float p = sX2[tid] * w3[tid];
    #pragma unroll
    for (int d = 1; d < 64; d <<= 1) p += __shfl_xor(p, d);
    if ((tid & 63) == 0) sR[tid >> 6] = p;
    __syncthreads();
    if (tid == 0) out[bq] = sR[0] + sR[1] + sR[2] + sR[3] + b3[0];
}

// ---------------------------------------------------------------------------
extern "C" void kernel_launch(void* const* d_in, const int* in_sizes, int n_in,
                              void* d_out, int out_size, void* d_ws, size_t ws_size,
                              hipStream_t stream)
{
    const float* feat0 = (const float*)d_in[0];
    const float* feat1 = (const float*)d_in[1];
    const float* feat2 = (const float*)d_in[2];
    const float* qe    = (const float*)d_in[3];
    const float* film_w0 = (const float*)d_in[4];
    const float* film_b0 = (const float*)d_in[5];
    const float* hid_w0  = (const float*)d_in[6];
    const float* hid_b0  = (const float*)d_in[7];
    const float* fin_w0  = (const float*)d_in[8];
    const float* fin_b0  = (const float*)d_in[9];
    const float* film_w1 = (const float*)d_in[10];
    const float* film_b1 = (const float*)d_in[11];
    const float* hid_w1  = (const float*)d_in[12];
    const float* hid_b1  = (const float*)d_in[13];
    const float* fin_w1  = (const float*)d_in[14];
    const float* fin_b1  = (const float*)d_in[15];
    const float* film_w2 = (const float*)d_in[16];
    const float* film_b2 = (const float*)d_in[17];
    const float* hid_w2  = (const float*)d_in[18];
    const float* hid_b2  = (const float*)d_in[19];
    const float* fin_w2  = (const float*)d_in[20];
    const float* fin_b2  = (const float*)d_in[21];
    const float* mlp_w1  = (const float*)d_in[22];
    const float* mlp_b1  = (const float*)d_in[23];
    const float* mlp_w2  = (const float*)d_in[24];
    const float* mlp_b2  = (const float*)d_in[25];
    const float* mlp_w3  = (const float*)d_in[26];
    const float* mlp_b3  = (const float*)d_in[27];

    float* ws = (float*)d_ws;
    float* S0    = ws;              // [64][65]
    float* S1    = ws + 4160;       // [64][129]
    float* S2    = ws + 12416;      // [64][257]   (Sout end 28864)
    float* gb0   = ws + 28864;      // [64][128]
    float* gb1   = ws + 37056;      // [64][256]
    float* gb2   = ws + 53440;      // [64][512]
    float* b20   = ws + 86208;      // [64][128]
    float* b21   = ws + 94400;
    float* b22   = ws + 102592;
    float* attn2 = ws + 110784;     // [64][400]
    float* X1    = ws + 136384;     // [64][512]   (end 169152 floats)

    hipMemsetAsync(d_ws, 0, 28864 * sizeof(float), stream);

    film_fused<<<dim3(BQ, 3), 256, 0, stream>>>(
        qe,
        film_w0, film_b0, hid_w0, hid_b0,
        film_w1, film_b1, hid_w1, hid_b1,
        film_w2, film_b2, hid_w2, hid_b2,
        gb0, gb1, gb2, b20, b21, b22);

    pool_fused<<<4288, 256, 0, stream>>>(
        feat0, feat1, feat2,
        gb0, gb1, gb2, b20, b21, b22,
        hid_w0, hid_w1, hid_w2,
        fin_w0, fin_b0, fin_w1, fin_b1, fin_w2, fin_b2,
        S0, S1, S2, attn2);

    mlp1_kernel<<<dim3(BQ, 2), 256, 0, stream>>>(
        S0, S1, S2, gb0, gb1, gb2, attn2, mlp_w1, mlp_b1, X1);

    mlp23_kernel<<<BQ, 256, 0, stream>>>(
        X1, mlp_w2, mlp_b2, mlp_w3, mlp_b3, (float*)d_out);
}